// Round 1
// baseline (366.951 us; speedup 1.0000x reference)
//
#include <hip/hip_runtime.h>
#include <hip/hip_bf16.h>

// Problem constants (BayesianLinear): IN_F=64, OUT_F=32, N=2080, B*S=16384
#define IN_F  64
#define OUT_F 32
#define NV    2080           // N
#define NPAD  2176           // 17*128
#define MM    16384          // tokens
#define KK    2080           // contraction dim

typedef __attribute__((ext_vector_type(4))) float f32x4;
typedef __bf16 bf16x8 __attribute__((ext_vector_type(8)));

using gas_ptr = const __attribute__((address_space(1))) void*;
using lds_ptr = __attribute__((address_space(3))) void*;

// ---------------------------------------------------------------------------
// Kernel 1: build L (bf16, row-major [NPAD][KK]); rows >= NV are zero.
// L[m][k] = cov_flat[m(m-1)/2 + k] for k<m ; exp(0.5*logvar[m]) for k==m ; 0 else
// ---------------------------------------------------------------------------
__global__ __launch_bounds__(256) void build_L_k(const float* __restrict__ cov,
                                                 const float* __restrict__ logvar,
                                                 __hip_bfloat16* __restrict__ LB) {
    const int idx = blockIdx.x * 256 + threadIdx.x;   // over NPAD*KK = 4,526,080
    const int m = idx / KK;
    const int k = idx - m * KK;
    float v = 0.0f;
    if (m < NV) {
        if (k < m)       v = cov[(size_t)(m * (m - 1) / 2) + k];
        else if (k == m) v = expf(0.5f * logvar[m]);
    }
    LB[idx] = __float2bfloat16(v);
}

// ---------------------------------------------------------------------------
// Kernel 2: eps fp32 -> bf16 (vectorized: float4 in, 4x bf16 out)
// ---------------------------------------------------------------------------
__global__ __launch_bounds__(256) void cvt_bf16_k(const float4* __restrict__ in,
                                                  ushort4* __restrict__ out) {
    const size_t i = (size_t)blockIdx.x * 256 + threadIdx.x;   // MM*KK/4 elements
    float4 v = in[i];
    union { ushort4 u; __hip_bfloat16 h[4]; } o;
    o.h[0] = __float2bfloat16(v.x);
    o.h[1] = __float2bfloat16(v.y);
    o.h[2] = __float2bfloat16(v.z);
    o.h[3] = __float2bfloat16(v.w);
    out[i] = o.u;
}

// ---------------------------------------------------------------------------
// Kernel 3: Z = Eps (MMxKK) * L^T, gemm_bt style: Z[t][m] = sum_k Eps[t,k]*L[m,k]
// 128x128 block tile, BK=32, 4 waves each computing 64x64 via 4x4 mfma 16x16x32.
// Triangular cut: column tile bn only needs kb < min(65, 4*bn+4).
// Z stored bf16 with row stride NPAD.
// ---------------------------------------------------------------------------
__global__ __launch_bounds__(256) void gemm_zl_k(const __hip_bfloat16* __restrict__ A,
                                                 const __hip_bfloat16* __restrict__ BT,
                                                 __hip_bfloat16* __restrict__ Z) {
    __shared__ __align__(16) __hip_bfloat16 As[128 * 32];
    __shared__ __align__(16) __hip_bfloat16 Bs[128 * 32];

    const int tid  = threadIdx.x;
    const int bm   = blockIdx.x;      // 0..127 (M tiles)
    const int bn   = blockIdx.y;      // 0..16  (N tiles, padded)
    const int wave = tid >> 6;
    const int lane = tid & 63;
    const int wr   = wave >> 1;       // wave row (0..1)
    const int wc   = wave & 1;        // wave col (0..1)
    const int quad = lane >> 4;       // 0..3
    const int r16  = lane & 15;

    const int kblocks = min(KK / 32, 4 * bn + 4);   // triangular truncation

    const __hip_bfloat16* Ag = A  + (size_t)bm * 128 * KK;
    const __hip_bfloat16* Bg = BT + (size_t)bn * 128 * KK;

    // staging chunks: 512 x 16B per tile; chunk c -> row=c>>2, colByteOff=(c&3)*8 elems
    const int c0 = tid, c1 = tid + 256;
    const int ar0 = c0 >> 2, ao0 = (c0 & 3) * 8;
    const int ar1 = c1 >> 2, ao1 = (c1 & 3) * 8;

    f32x4 acc[4][4];
#pragma unroll
    for (int i = 0; i < 4; i++)
#pragma unroll
        for (int j = 0; j < 4; j++) acc[i][j] = f32x4{0.f, 0.f, 0.f, 0.f};

    for (int kb = 0; kb < kblocks; ++kb) {
        const int k0 = kb * 32;
        __builtin_amdgcn_global_load_lds((gas_ptr)(Ag + (size_t)ar0 * KK + k0 + ao0),
                                         (lds_ptr)(As + c0 * 8), 16, 0, 0);
        __builtin_amdgcn_global_load_lds((gas_ptr)(Ag + (size_t)ar1 * KK + k0 + ao1),
                                         (lds_ptr)(As + c1 * 8), 16, 0, 0);
        __builtin_amdgcn_global_load_lds((gas_ptr)(Bg + (size_t)ar0 * KK + k0 + ao0),
                                         (lds_ptr)(Bs + c0 * 8), 16, 0, 0);
        __builtin_amdgcn_global_load_lds((gas_ptr)(Bg + (size_t)ar1 * KK + k0 + ao1),
                                         (lds_ptr)(Bs + c1 * 8), 16, 0, 0);
        asm volatile("s_waitcnt vmcnt(0)" ::: "memory");
        __syncthreads();

        bf16x8 af[4], bfr[4];
#pragma unroll
        for (int i = 0; i < 4; i++)
            af[i] = *(const bf16x8*)(As + (64 * wr + 16 * i + r16) * 32 + quad * 8);
#pragma unroll
        for (int j = 0; j < 4; j++)
            bfr[j] = *(const bf16x8*)(Bs + (64 * wc + 16 * j + r16) * 32 + quad * 8);
#pragma unroll
        for (int i = 0; i < 4; i++)
#pragma unroll
            for (int j = 0; j < 4; j++)
                acc[i][j] = __builtin_amdgcn_mfma_f32_16x16x32_bf16(af[i], bfr[j], acc[i][j], 0, 0, 0);
        __syncthreads();
    }

    // C/D layout (verified m89): col = lane&15, row = quad*4 + reg
#pragma unroll
    for (int i = 0; i < 4; i++) {
#pragma unroll
        for (int j = 0; j < 4; j++) {
            const int row0 = bm * 128 + 64 * wr + 16 * i + quad * 4;
            const int col  = bn * 128 + 64 * wc + 16 * j + r16;
#pragma unroll
            for (int r = 0; r < 4; r++)
                Z[(size_t)(row0 + r) * NPAD + col] = __float2bfloat16(acc[i][j][r]);
        }
    }
}

// ---------------------------------------------------------------------------
// Kernel 4: epilogue.  y[t,k] = (loc[k]+z[t,k]) + sum_h x[t,h]*(loc[32+32h+k]+z[t,32+32h+k])
// 256 threads = 8 tokens x 32 k-lanes per block.
// ---------------------------------------------------------------------------
__global__ __launch_bounds__(256) void epilogue_k(const __hip_bfloat16* __restrict__ Z,
                                                  const float* __restrict__ x,
                                                  const float* __restrict__ loc,
                                                  float* __restrict__ y) {
    __shared__ float locs[NV];
    __shared__ float xs[8][IN_F];
    const int tid = threadIdx.x;
    const int t0  = blockIdx.x * 8;
    for (int i = tid; i < NV; i += 256) locs[i] = loc[i];
    {
        int i = tid;
        xs[i >> 6][i & 63] = x[(size_t)(t0 + (i >> 6)) * IN_F + (i & 63)];
        i += 256;
        xs[i >> 6][i & 63] = x[(size_t)(t0 + (i >> 6)) * IN_F + (i & 63)];
    }
    __syncthreads();

    const int k  = tid & 31;
    const int tl = tid >> 5;
    const size_t t = (size_t)t0 + tl;
    const __hip_bfloat16* zr = Z + t * NPAD;

    float sum = locs[k] + __bfloat162float(zr[k]);   // bias term W[k]
#pragma unroll 8
    for (int h = 0; h < IN_F; ++h) {
        const int m = OUT_F + (h << 5) + k;
        sum += xs[tl][h] * (locs[m] + __bfloat162float(zr[m]));
    }
    y[t * OUT_F + k] = sum;
}

// ---------------------------------------------------------------------------
extern "C" void kernel_launch(void* const* d_in, const int* in_sizes, int n_in,
                              void* d_out, int out_size, void* d_ws, size_t ws_size,
                              hipStream_t stream) {
    const float* x      = (const float*)d_in[0];
    const float* eps    = (const float*)d_in[1];
    const float* loc    = (const float*)d_in[2];
    const float* logvar = (const float*)d_in[3];
    const float* cov    = (const float*)d_in[4];
    float* y = (float*)d_out;

    char* ws = (char*)d_ws;
    __hip_bfloat16* EpsB = (__hip_bfloat16*)ws;                                   // MM*KK bf16 (68.2 MB)
    __hip_bfloat16* LB   = (__hip_bfloat16*)(ws + (size_t)MM * KK * 2);           // NPAD*KK bf16 (9.1 MB)
    __hip_bfloat16* Zb   = (__hip_bfloat16*)(ws + (size_t)MM * KK * 2
                                                + (size_t)NPAD * KK * 2);         // MM*NPAD bf16 (71.3 MB)

    build_L_k<<<(NPAD * KK) / 256, 256, 0, stream>>>(cov, logvar, LB);
    cvt_bf16_k<<<(MM * KK / 4) / 256, 256, 0, stream>>>((const float4*)eps, (ushort4*)EpsB);
    gemm_zl_k<<<dim3(MM / 128, NPAD / 128), 256, 0, stream>>>(EpsB, LB, Zb);
    epilogue_k<<<MM / 8, 256, 0, stream>>>(Zb, x, loc, y);
}

// Round 2
// 338.191 us; speedup vs baseline: 1.0850x; 1.0850x over previous
//
#include <hip/hip_runtime.h>
#include <hip/hip_bf16.h>

// Problem constants (BayesianLinear): IN_F=64, OUT_F=32, N=2080, B*S=16384
#define IN_F  64
#define OUT_F 32
#define NV    2080           // N
#define NPAD  2176           // 17*128
#define MM    16384          // tokens
#define KK    2080           // contraction dim

typedef __attribute__((ext_vector_type(4))) float f32x4;
typedef __bf16 bf16x8 __attribute__((ext_vector_type(8)));

using gas_ptr = const __attribute__((address_space(1))) void*;
using lds_ptr = __attribute__((address_space(3))) void*;

// ---------------------------------------------------------------------------
// Kernel 1: build L (bf16, row-major [NPAD][KK]); rows >= NV are zero.
// ---------------------------------------------------------------------------
__global__ __launch_bounds__(256) void build_L_k(const float* __restrict__ cov,
                                                 const float* __restrict__ logvar,
                                                 __hip_bfloat16* __restrict__ LB) {
    const int idx = blockIdx.x * 256 + threadIdx.x;   // over NPAD*KK
    const int m = idx / KK;
    const int k = idx - m * KK;
    float v = 0.0f;
    if (m < NV) {
        if (k < m)       v = cov[(size_t)(m * (m - 1) / 2) + k];
        else if (k == m) v = expf(0.5f * logvar[m]);
    }
    LB[idx] = __float2bfloat16(v);
}

// ---------------------------------------------------------------------------
// Kernel 2: eps fp32 -> bf16, 8 floats/thread (32B read, 16B store)
// ---------------------------------------------------------------------------
__global__ __launch_bounds__(256) void cvt_bf16_k(const float4* __restrict__ in,
                                                  uint4* __restrict__ out) {
    const size_t i = (size_t)blockIdx.x * 256 + threadIdx.x;   // MM*KK/8 iters
    float4 a = in[2 * i];
    float4 b = in[2 * i + 1];
    union { uint4 u; __hip_bfloat16 h[8]; } o;
    o.h[0] = __float2bfloat16(a.x); o.h[1] = __float2bfloat16(a.y);
    o.h[2] = __float2bfloat16(a.z); o.h[3] = __float2bfloat16(a.w);
    o.h[4] = __float2bfloat16(b.x); o.h[5] = __float2bfloat16(b.y);
    o.h[6] = __float2bfloat16(b.z); o.h[7] = __float2bfloat16(b.w);
    out[i] = o.u;
}

// ---------------------------------------------------------------------------
// Kernel 3: Z = Eps (MMxKK) * L^T. 128x128 tile, BK=32, 4 waves of 64x64.
// XOR-swizzled LDS (kills bank conflicts), double-buffered single-barrier
// pipeline (staging of kb+1 overlaps MFMA of kb; next barrier's implicit
// vmcnt(0) is the drain). Triangular cut: kblocks = min(65, 4*bn+4).
// ---------------------------------------------------------------------------
__global__ __launch_bounds__(256) void gemm_zl_k(const __hip_bfloat16* __restrict__ A,
                                                 const __hip_bfloat16* __restrict__ BT,
                                                 __hip_bfloat16* __restrict__ Z) {
    // [buf][128 rows][32 elems]; slot (row, p) holds global part p^((row>>1)&3)
    __shared__ __align__(16) __hip_bfloat16 As[2][128 * 32];
    __shared__ __align__(16) __hip_bfloat16 Bs[2][128 * 32];

    const int tid  = threadIdx.x;
    const int bm   = blockIdx.x;            // 0..127 (M tiles)
    const int bn   = 16 - blockIdx.y;       // 0..16, heaviest (bn=16) first
    const int wave = tid >> 6;
    const int lane = tid & 63;
    const int wr   = wave >> 1;             // wave row (0..1)
    const int wc   = wave & 1;              // wave col (0..1)
    const int quad = lane >> 4;             // 0..3
    const int r16  = lane & 15;

    const int kblocks = min(KK / 32, 4 * bn + 4);   // triangular truncation

    const __hip_bfloat16* Ag = A  + (size_t)bm * 128 * KK;
    const __hip_bfloat16* Bg = BT + (size_t)bn * 128 * KK;

    // staging chunks: 512 x 16B per tile; chunk c -> LDS slot (c>>2, c&3);
    // that slot must hold global part (c&3) ^ (((c>>2)>>1)&3)
    const int c0 = tid, c1 = tid + 256;
    const int ar0 = c0 >> 2, ap0 = (c0 & 3) ^ ((ar0 >> 1) & 3);
    const int ar1 = c1 >> 2, ap1 = (c1 & 3) ^ ((ar1 >> 1) & 3);
    const size_t gofs0 = (size_t)ar0 * KK + ap0 * 8;
    const size_t gofs1 = (size_t)ar1 * KK + ap1 * 8;

    f32x4 acc[4][4];
#pragma unroll
    for (int i = 0; i < 4; i++)
#pragma unroll
        for (int j = 0; j < 4; j++) acc[i][j] = f32x4{0.f, 0.f, 0.f, 0.f};

    // fragment-read LDS offsets (elements), swizzled
    int aofs[4], bofs[4];
#pragma unroll
    for (int i = 0; i < 4; i++) {
        const int arow = 64 * wr + 16 * i + r16;
        aofs[i] = arow * 32 + (quad ^ ((arow >> 1) & 3)) * 8;
        const int brow = 64 * wc + 16 * i + r16;
        bofs[i] = brow * 32 + (quad ^ ((brow >> 1) & 3)) * 8;
    }

    // prologue: stage tile 0 into buf 0
    __builtin_amdgcn_global_load_lds((gas_ptr)(Ag + gofs0), (lds_ptr)(&As[0][0] + c0 * 8), 16, 0, 0);
    __builtin_amdgcn_global_load_lds((gas_ptr)(Ag + gofs1), (lds_ptr)(&As[0][0] + c1 * 8), 16, 0, 0);
    __builtin_amdgcn_global_load_lds((gas_ptr)(Bg + gofs0), (lds_ptr)(&Bs[0][0] + c0 * 8), 16, 0, 0);
    __builtin_amdgcn_global_load_lds((gas_ptr)(Bg + gofs1), (lds_ptr)(&Bs[0][0] + c1 * 8), 16, 0, 0);

    for (int kb = 0; kb < kblocks; ++kb) {
        const int cur = kb & 1;
        __syncthreads();   // implicit vmcnt(0): buf[cur] staging complete everywhere

        if (kb + 1 < kblocks) {   // prefetch next tile into buf[cur^1]; drains at NEXT barrier
            const size_t k0 = (size_t)(kb + 1) * 32;
            __builtin_amdgcn_global_load_lds((gas_ptr)(Ag + k0 + gofs0), (lds_ptr)(&As[cur ^ 1][0] + c0 * 8), 16, 0, 0);
            __builtin_amdgcn_global_load_lds((gas_ptr)(Ag + k0 + gofs1), (lds_ptr)(&As[cur ^ 1][0] + c1 * 8), 16, 0, 0);
            __builtin_amdgcn_global_load_lds((gas_ptr)(Bg + k0 + gofs0), (lds_ptr)(&Bs[cur ^ 1][0] + c0 * 8), 16, 0, 0);
            __builtin_amdgcn_global_load_lds((gas_ptr)(Bg + k0 + gofs1), (lds_ptr)(&Bs[cur ^ 1][0] + c1 * 8), 16, 0, 0);
        }

        bf16x8 af[4], bfr[4];
#pragma unroll
        for (int i = 0; i < 4; i++) af[i]  = *(const bf16x8*)(&As[cur][0] + aofs[i]);
#pragma unroll
        for (int j = 0; j < 4; j++) bfr[j] = *(const bf16x8*)(&Bs[cur][0] + bofs[j]);
#pragma unroll
        for (int i = 0; i < 4; i++)
#pragma unroll
            for (int j = 0; j < 4; j++)
                acc[i][j] = __builtin_amdgcn_mfma_f32_16x16x32_bf16(af[i], bfr[j], acc[i][j], 0, 0, 0);
    }

    // C/D layout (m89): col = lane&15, row = quad*4 + reg
#pragma unroll
    for (int i = 0; i < 4; i++) {
#pragma unroll
        for (int j = 0; j < 4; j++) {
            const int row0 = bm * 128 + 64 * wr + 16 * i + quad * 4;
            const int col  = bn * 128 + 64 * wc + 16 * j + r16;
#pragma unroll
            for (int r = 0; r < 4; r++)
                Z[(size_t)(row0 + r) * NPAD + col] = __float2bfloat16(acc[i][j][r]);
        }
    }
}

// ---------------------------------------------------------------------------
// Kernel 4: epilogue.  y[t,k] = (loc[k]+z[t,k]) + sum_h x[t,h]*(loc[32+32h+k]+z[t,32+32h+k])
// ---------------------------------------------------------------------------
__global__ __launch_bounds__(256) void epilogue_k(const __hip_bfloat16* __restrict__ Z,
                                                  const float* __restrict__ x,
                                                  const float* __restrict__ loc,
                                                  float* __restrict__ y) {
    __shared__ float locs[NV];
    __shared__ float xs[8][IN_F];
    const int tid = threadIdx.x;
    const int t0  = blockIdx.x * 8;
    for (int i = tid; i < NV; i += 256) locs[i] = loc[i];
    {
        int i = tid;
        xs[i >> 6][i & 63] = x[(size_t)(t0 + (i >> 6)) * IN_F + (i & 63)];
        i += 256;
        xs[i >> 6][i & 63] = x[(size_t)(t0 + (i >> 6)) * IN_F + (i & 63)];
    }
    __syncthreads();

    const int k  = tid & 31;
    const int tl = tid >> 5;
    const size_t t = (size_t)t0 + tl;
    const __hip_bfloat16* zr = Z + t * NPAD;

    float sum = locs[k] + __bfloat162float(zr[k]);   // bias term W[k]
#pragma unroll 8
    for (int h = 0; h < IN_F; ++h) {
        const int m = OUT_F + (h << 5) + k;
        sum += xs[tl][h] * (locs[m] + __bfloat162float(zr[m]));
    }
    y[t * OUT_F + k] = sum;
}

// ---------------------------------------------------------------------------
extern "C" void kernel_launch(void* const* d_in, const int* in_sizes, int n_in,
                              void* d_out, int out_size, void* d_ws, size_t ws_size,
                              hipStream_t stream) {
    const float* x      = (const float*)d_in[0];
    const float* eps    = (const float*)d_in[1];
    const float* loc    = (const float*)d_in[2];
    const float* logvar = (const float*)d_in[3];
    const float* cov    = (const float*)d_in[4];
    float* y = (float*)d_out;

    char* ws = (char*)d_ws;
    __hip_bfloat16* EpsB = (__hip_bfloat16*)ws;                                   // MM*KK bf16
    __hip_bfloat16* LB   = (__hip_bfloat16*)(ws + (size_t)MM * KK * 2);           // NPAD*KK bf16
    __hip_bfloat16* Zb   = (__hip_bfloat16*)(ws + (size_t)MM * KK * 2
                                                + (size_t)NPAD * KK * 2);         // MM*NPAD bf16

    build_L_k<<<(NPAD * KK) / 256, 256, 0, stream>>>(cov, logvar, LB);
    cvt_bf16_k<<<(MM * KK / 8) / 256, 256, 0, stream>>>((const float4*)eps, (uint4*)EpsB);
    gemm_zl_k<<<dim3(MM / 128, NPAD / 128), 256, 0, stream>>>(EpsB, LB, Zb);
    epilogue_k<<<MM / 8, 256, 0, stream>>>(Zb, x, loc, y);
}

// Round 3
// 326.613 us; speedup vs baseline: 1.1235x; 1.0355x over previous
//
#include <hip/hip_runtime.h>
#include <hip/hip_bf16.h>

// Problem constants (BayesianLinear): IN_F=64, OUT_F=32, N=2080, B*S=16384
#define IN_F  64
#define OUT_F 32
#define NV    2080           // N
#define NPAD  2176           // 17*128
#define MM    16384          // tokens
#define KK    2080           // contraction dim

typedef __attribute__((ext_vector_type(4))) float f32x4;
typedef __bf16 bf16x8 __attribute__((ext_vector_type(8)));

using gas_ptr = const __attribute__((address_space(1))) void*;
using lds_ptr = __attribute__((address_space(3))) void*;

// ---------------------------------------------------------------------------
// Kernel 1: build L (bf16, row-major [NPAD][KK]); rows >= NV are zero.
// ---------------------------------------------------------------------------
__global__ __launch_bounds__(256) void build_L_k(const float* __restrict__ cov,
                                                 const float* __restrict__ logvar,
                                                 __hip_bfloat16* __restrict__ LB) {
    const int idx = blockIdx.x * 256 + threadIdx.x;   // over NPAD*KK
    const int m = idx / KK;
    const int k = idx - m * KK;
    float v = 0.0f;
    if (m < NV) {
        if (k < m)       v = cov[(size_t)(m * (m - 1) / 2) + k];
        else if (k == m) v = expf(0.5f * logvar[m]);
    }
    LB[idx] = __float2bfloat16(v);
}

// ---------------------------------------------------------------------------
// Kernel 2: Z' = Eps(f32, converted in-reg) * L^T + loc.  128x128 tile, BK=32.
// A staged as fp32 (16KB/tile) with xor swizzle part^=(row&7); fragment reads
// are two b128s converted to bf16x8 in registers. B staged bf16 as before.
// Double-buffered single-barrier pipeline; triangular cut kblocks=min(65,4bn+4).
// ---------------------------------------------------------------------------
__global__ __launch_bounds__(256) void gemm_zl_k(const float* __restrict__ A,
                                                 const __hip_bfloat16* __restrict__ BT,
                                                 const float* __restrict__ loc,
                                                 __hip_bfloat16* __restrict__ Z) {
    // A: [buf][128 rows][32 floats]; slot(row,ps) holds global part ps^(row&7) (parts of 4 floats)
    // B: [buf][128 rows][32 bf16]; slot(row,p) holds global part p^((row>>1)&3) (parts of 8 bf16)
    __shared__ __align__(16) float          As[2][128 * 32];
    __shared__ __align__(16) __hip_bfloat16 Bs[2][128 * 32];

    const int tid  = threadIdx.x;
    const int bm   = blockIdx.x;            // 0..127 (M tiles)
    const int bn   = 16 - blockIdx.y;       // 0..16, heaviest (bn=16) first
    const int wave = tid >> 6;
    const int lane = tid & 63;
    const int wr   = wave >> 1;             // wave row (0..1)
    const int wc   = wave & 1;              // wave col (0..1)
    const int quad = lane >> 4;             // 0..3
    const int r16  = lane & 15;

    const int kblocks = min(KK / 32, 4 * bn + 4);   // triangular truncation

    const float*          Ag = A  + (size_t)bm * 128 * KK;
    const __hip_bfloat16* Bg = BT + (size_t)bn * 128 * KK;

    // A staging: 1024 chunks of 16B (4 floats). chunk c -> LDS slot (c>>3, c&7),
    // holding global part (c&7)^(row&7).
    int aldsofs[4];          // float offset in As buffer
    size_t agofs[4];         // float offset in global A tile
#pragma unroll
    for (int i = 0; i < 4; i++) {
        const int c   = tid + 256 * i;
        const int row = c >> 3;
        const int pg  = (c & 7) ^ (row & 7);
        aldsofs[i] = c * 4;
        agofs[i]   = (size_t)row * KK + pg * 4;
    }
    // B staging: 512 chunks of 16B (8 bf16). chunk c -> slot (c>>2, c&3),
    // holding global part (c&3)^((row>>1)&3).
    const int c0 = tid, c1 = tid + 256;
    const int br0 = c0 >> 2, bp0 = (c0 & 3) ^ ((br0 >> 1) & 3);
    const int br1 = c1 >> 2, bp1 = (c1 & 3) ^ ((br1 >> 1) & 3);
    const size_t bgofs0 = (size_t)br0 * KK + bp0 * 8;
    const size_t bgofs1 = (size_t)br1 * KK + bp1 * 8;

    f32x4 acc[4][4];
#pragma unroll
    for (int i = 0; i < 4; i++)
#pragma unroll
        for (int j = 0; j < 4; j++) acc[i][j] = f32x4{0.f, 0.f, 0.f, 0.f};

    // fragment-read LDS offsets
    int aofs0[4], aofs1[4], bofs[4];
#pragma unroll
    for (int i = 0; i < 4; i++) {
        const int arow = 64 * wr + 16 * i + r16;
        const int s0 = (2 * quad) ^ (arow & 7);
        const int s1 = (2 * quad + 1) ^ (arow & 7);
        aofs0[i] = arow * 32 + s0 * 4;      // floats: global k-parts quad*8..+3
        aofs1[i] = arow * 32 + s1 * 4;      // floats: global k-parts quad*8+4..+7
        const int brow = 64 * wc + 16 * i + r16;
        bofs[i] = brow * 32 + (quad ^ ((brow >> 1) & 3)) * 8;
    }

    // prologue: stage tile 0 into buf 0
#pragma unroll
    for (int i = 0; i < 4; i++)
        __builtin_amdgcn_global_load_lds((gas_ptr)(Ag + agofs[i]), (lds_ptr)(&As[0][0] + aldsofs[i]), 16, 0, 0);
    __builtin_amdgcn_global_load_lds((gas_ptr)(Bg + bgofs0), (lds_ptr)(&Bs[0][0] + c0 * 8), 16, 0, 0);
    __builtin_amdgcn_global_load_lds((gas_ptr)(Bg + bgofs1), (lds_ptr)(&Bs[0][0] + c1 * 8), 16, 0, 0);

    for (int kb = 0; kb < kblocks; ++kb) {
        const int cur = kb & 1;
        __syncthreads();   // implicit vmcnt(0): buf[cur] staging complete everywhere

        if (kb + 1 < kblocks) {   // prefetch next tile into buf[cur^1]; drains at NEXT barrier
            const size_t k0 = (size_t)(kb + 1) * 32;
#pragma unroll
            for (int i = 0; i < 4; i++)
                __builtin_amdgcn_global_load_lds((gas_ptr)(Ag + k0 + agofs[i]),
                                                 (lds_ptr)(&As[cur ^ 1][0] + aldsofs[i]), 16, 0, 0);
            __builtin_amdgcn_global_load_lds((gas_ptr)(Bg + k0 + bgofs0), (lds_ptr)(&Bs[cur ^ 1][0] + c0 * 8), 16, 0, 0);
            __builtin_amdgcn_global_load_lds((gas_ptr)(Bg + k0 + bgofs1), (lds_ptr)(&Bs[cur ^ 1][0] + c1 * 8), 16, 0, 0);
        }

        bf16x8 af[4], bfr[4];
#pragma unroll
        for (int i = 0; i < 4; i++) {
            const f32x4 f0 = *(const f32x4*)(&As[cur][0] + aofs0[i]);
            const f32x4 f1 = *(const f32x4*)(&As[cur][0] + aofs1[i]);
            bf16x8 a;
            a[0] = (__bf16)f0[0]; a[1] = (__bf16)f0[1]; a[2] = (__bf16)f0[2]; a[3] = (__bf16)f0[3];
            a[4] = (__bf16)f1[0]; a[5] = (__bf16)f1[1]; a[6] = (__bf16)f1[2]; a[7] = (__bf16)f1[3];
            af[i] = a;
        }
#pragma unroll
        for (int j = 0; j < 4; j++) bfr[j] = *(const bf16x8*)(&Bs[cur][0] + bofs[j]);
#pragma unroll
        for (int i = 0; i < 4; i++)
#pragma unroll
            for (int j = 0; j < 4; j++)
                acc[i][j] = __builtin_amdgcn_mfma_f32_16x16x32_bf16(af[i], bfr[j], acc[i][j], 0, 0, 0);
    }

    // epilogue: Z' = acc + loc[col].  C/D layout (m89): col=lane&15, row=quad*4+reg
    float locv[4];
#pragma unroll
    for (int j = 0; j < 4; j++) {
        const int col = bn * 128 + 64 * wc + 16 * j + r16;
        locv[j] = (col < NV) ? loc[col] : 0.0f;
    }
#pragma unroll
    for (int i = 0; i < 4; i++) {
#pragma unroll
        for (int j = 0; j < 4; j++) {
            const int row0 = bm * 128 + 64 * wr + 16 * i + quad * 4;
            const int col  = bn * 128 + 64 * wc + 16 * j + r16;
#pragma unroll
            for (int r = 0; r < 4; r++)
                Z[(size_t)(row0 + r) * NPAD + col] = __float2bfloat16(acc[i][j][r] + locv[j]);
        }
    }
}

// ---------------------------------------------------------------------------
// Kernel 3: epilogue. One wave per token. W' row (2080 bf16, already + loc)
// staged to LDS via b128 loads; halves of the wave split h<32 / h>=32;
// combine via shuffle.  y[t,k] = W'[k] + sum_h x[t,h]*W'[32+32h+k]
// ---------------------------------------------------------------------------
__global__ __launch_bounds__(256) void epilogue_k(const __hip_bfloat16* __restrict__ Z,
                                                  const float* __restrict__ x,
                                                  float* __restrict__ y) {
    __shared__ __align__(16) __hip_bfloat16 Ws[4][NV];   // 4 waves x 4160 B
    __shared__ float xsm[4][IN_F];
    const int tid  = threadIdx.x;
    const int wave = tid >> 6;
    const int lane = tid & 63;
    const size_t t = (size_t)blockIdx.x * 4 + wave;

    {
        const uint4* src = (const uint4*)(Z + t * NPAD);
        uint4* dst = (uint4*)&Ws[wave][0];
#pragma unroll
        for (int i = 0; i < 4; i++) dst[lane + 64 * i] = src[lane + 64 * i];   // chunks 0..255
        if (lane < 4) dst[256 + lane] = src[256 + lane];                       // chunks 256..259
        xsm[wave][lane & 63] = x[t * IN_F + lane];
    }
    __syncthreads();

    const int k    = lane & 31;
    const int half = lane >> 5;          // 0: h<32 (+bias), 1: h>=32
    float s = (half == 0) ? __bfloat162float(Ws[wave][k]) : 0.0f;
#pragma unroll
    for (int j = 0; j < 32; j++) {
        const int h = half * 32 + j;
        s += xsm[wave][h] * __bfloat162float(Ws[wave][OUT_F + (h << 5) + k]);
    }
    const float other = __shfl(s, k + 32);   // high-half partial
    if (half == 0) y[t * OUT_F + k] = s + other;
}

// ---------------------------------------------------------------------------
extern "C" void kernel_launch(void* const* d_in, const int* in_sizes, int n_in,
                              void* d_out, int out_size, void* d_ws, size_t ws_size,
                              hipStream_t stream) {
    const float* x      = (const float*)d_in[0];
    const float* eps    = (const float*)d_in[1];
    const float* loc    = (const float*)d_in[2];
    const float* logvar = (const float*)d_in[3];
    const float* cov    = (const float*)d_in[4];
    float* y = (float*)d_out;

    char* ws = (char*)d_ws;
    __hip_bfloat16* LB = (__hip_bfloat16*)ws;                                // NPAD*KK bf16 (9.1 MB)
    __hip_bfloat16* Zb = (__hip_bfloat16*)(ws + (size_t)NPAD * KK * 2);      // MM*NPAD bf16 (71.3 MB)

    build_L_k<<<(NPAD * KK) / 256, 256, 0, stream>>>(cov, logvar, LB);
    gemm_zl_k<<<dim3(MM / 128, NPAD / 128), 256, 0, stream>>>(eps, LB, loc, Zb);
    epilogue_k<<<MM / 4, 256, 0, stream>>>(Zb, x, y);
}

// Round 5
// 323.148 us; speedup vs baseline: 1.1356x; 1.0107x over previous
//
#include <hip/hip_runtime.h>
#include <hip/hip_bf16.h>

// Problem constants (BayesianLinear): IN_F=64, OUT_F=32, N=2080, B*S=16384
#define IN_F  64
#define OUT_F 32
#define NV    2080           // N
#define NPAD  2176           // 17*128
#define MM    16384          // tokens
#define KK    2080           // contraction dim
#define NBN   17             // column tiles

#define NB_CVT (MM * KK / 8 / 256)    // 16640 blocks for eps fp32->bf16
#define NB_L   (NPAD * KK / 256)      // 17680 blocks for build_L

typedef __attribute__((ext_vector_type(4))) float f32x4;
typedef __bf16 bf16x8 __attribute__((ext_vector_type(8)));

using gas_ptr = const __attribute__((address_space(1))) void*;
using lds_ptr = __attribute__((address_space(3))) void*;

// ---------------------------------------------------------------------------
// Kernel 1: prep = cvt(eps fp32->bf16) + build_L, fused via blockIdx split.
// ---------------------------------------------------------------------------
__global__ __launch_bounds__(256) void prep_k(const float* __restrict__ cov,
                                              const float* __restrict__ logvar,
                                              const float4* __restrict__ eps4,
                                              uint4* __restrict__ epsb,
                                              __hip_bfloat16* __restrict__ LB) {
    if (blockIdx.x < NB_CVT) {
        const size_t i = (size_t)blockIdx.x * 256 + threadIdx.x;
        float4 a = eps4[2 * i];
        float4 b = eps4[2 * i + 1];
        union { uint4 u; __hip_bfloat16 h[8]; } o;
        o.h[0] = __float2bfloat16(a.x); o.h[1] = __float2bfloat16(a.y);
        o.h[2] = __float2bfloat16(a.z); o.h[3] = __float2bfloat16(a.w);
        o.h[4] = __float2bfloat16(b.x); o.h[5] = __float2bfloat16(b.y);
        o.h[6] = __float2bfloat16(b.z); o.h[7] = __float2bfloat16(b.w);
        epsb[i] = o.u;
    } else {
        const int idx = (blockIdx.x - NB_CVT) * 256 + threadIdx.x;   // over NPAD*KK
        const int m = idx / KK;
        const int k = idx - m * KK;
        float v = 0.0f;
        if (m < NV) {
            if (k < m)       v = cov[(size_t)(m * (m - 1) / 2) + k];
            else if (k == m) v = expf(0.5f * logvar[m]);
        }
        LB[idx] = __float2bfloat16(v);
    }
}

// ---------------------------------------------------------------------------
// Kernel 2: fused GEMM + in-lane x-contraction.
// K-loop identical to R2's proven structure (bf16 A/B, xor swizzle, dbuf
// single-barrier).  Wave tiling: 4 row-strips of 32 rows x full 128 cols
// (acc[2][8]) so each wave holds all 4 h-columns (c=j>>1) of its rows ->
// the contraction y_part[t,k] = sum_c xs[t][c]*(W[t,col]+...) is fully
// in-register; direct store to Ypart slab bn.  No cross-wave combine.
// Column mapping: col=128bn+16j+r16 -> c=j>>1, k=16*(j&1)+r16;
// bn==0,c==0 is the bias region (weight 1).
// ---------------------------------------------------------------------------
__global__ __launch_bounds__(256) void gemm_zl_k(const __hip_bfloat16* __restrict__ A,
                                                 const __hip_bfloat16* __restrict__ BT,
                                                 const float* __restrict__ loc,
                                                 const float* __restrict__ x,
                                                 float* __restrict__ Ypart) {
    __shared__ __align__(16) __hip_bfloat16 As[2][128 * 32];
    __shared__ __align__(16) __hip_bfloat16 Bs[2][128 * 32];
    __shared__ float xs[128][4];

    const int tid  = threadIdx.x;
    const int bm   = blockIdx.x;             // 0..127 (M tiles)
    const int bn   = (NBN - 1) - blockIdx.y; // 0..16, heaviest (bn=16) first
    const int wave = tid >> 6;
    const int lane = tid & 63;
    const int quad = lane >> 4;              // 0..3
    const int r16  = lane & 15;

    const int kblocks = min(KK / 32, 4 * bn + 4);   // triangular truncation

    // stage xs: weight for h = 4bn-1+c; bias (1.0) at bn==0,c==0; 0 if h invalid
    {
        const int tl = tid >> 1;
        const int cc = (tid & 1) * 2;
#pragma unroll
        for (int c = cc; c < cc + 2; c++) {
            const int h = 4 * bn - 1 + c;
            float w = 0.0f;
            if (bn == 0 && c == 0)          w = 1.0f;
            else if (h >= 0 && h < IN_F)    w = x[(size_t)(bm * 128 + tl) * IN_F + h];
            xs[tl][c] = w;
        }
    }

    const __hip_bfloat16* Ag = A  + (size_t)bm * 128 * KK;
    const __hip_bfloat16* Bg = BT + (size_t)bn * 128 * KK;

    // staging: 512 chunks of 16B (8 bf16); chunk c -> slot (c>>2, c&3),
    // holding global part (c&3)^((row>>1)&3).
    const int c0 = tid, c1 = tid + 256;
    const int ar0 = c0 >> 2, ap0 = (c0 & 3) ^ ((ar0 >> 1) & 3);
    const int ar1 = c1 >> 2, ap1 = (c1 & 3) ^ ((ar1 >> 1) & 3);
    const size_t gofs0 = (size_t)ar0 * KK + ap0 * 8;
    const size_t gofs1 = (size_t)ar1 * KK + ap1 * 8;

    f32x4 acc[2][8];
#pragma unroll
    for (int i = 0; i < 2; i++)
#pragma unroll
        for (int j = 0; j < 8; j++) acc[i][j] = f32x4{0.f, 0.f, 0.f, 0.f};

    // fragment-read LDS offsets (elements), swizzled
    int aofs[2], bofs[8];
#pragma unroll
    for (int i = 0; i < 2; i++) {
        const int arow = 32 * wave + 16 * i + r16;
        aofs[i] = arow * 32 + (quad ^ ((arow >> 1) & 3)) * 8;
    }
#pragma unroll
    for (int j = 0; j < 8; j++) {
        const int brow = 16 * j + r16;
        bofs[j] = brow * 32 + (quad ^ ((brow >> 1) & 3)) * 8;
    }

    // prologue: stage tile 0 into buf 0
    __builtin_amdgcn_global_load_lds((gas_ptr)(Ag + gofs0), (lds_ptr)(&As[0][0] + c0 * 8), 16, 0, 0);
    __builtin_amdgcn_global_load_lds((gas_ptr)(Ag + gofs1), (lds_ptr)(&As[0][0] + c1 * 8), 16, 0, 0);
    __builtin_amdgcn_global_load_lds((gas_ptr)(Bg + gofs0), (lds_ptr)(&Bs[0][0] + c0 * 8), 16, 0, 0);
    __builtin_amdgcn_global_load_lds((gas_ptr)(Bg + gofs1), (lds_ptr)(&Bs[0][0] + c1 * 8), 16, 0, 0);

    for (int kb = 0; kb < kblocks; ++kb) {
        const int cur = kb & 1;
        __syncthreads();   // implicit vmcnt(0): buf[cur] staging complete everywhere

        if (kb + 1 < kblocks) {   // prefetch next tile; drains at NEXT barrier
            const size_t k0 = (size_t)(kb + 1) * 32;
            __builtin_amdgcn_global_load_lds((gas_ptr)(Ag + k0 + gofs0), (lds_ptr)(&As[cur ^ 1][0] + c0 * 8), 16, 0, 0);
            __builtin_amdgcn_global_load_lds((gas_ptr)(Ag + k0 + gofs1), (lds_ptr)(&As[cur ^ 1][0] + c1 * 8), 16, 0, 0);
            __builtin_amdgcn_global_load_lds((gas_ptr)(Bg + k0 + gofs0), (lds_ptr)(&Bs[cur ^ 1][0] + c0 * 8), 16, 0, 0);
            __builtin_amdgcn_global_load_lds((gas_ptr)(Bg + k0 + gofs1), (lds_ptr)(&Bs[cur ^ 1][0] + c1 * 8), 16, 0, 0);
        }

        bf16x8 af[2], bfr[8];
#pragma unroll
        for (int i = 0; i < 2; i++) af[i]  = *(const bf16x8*)(&As[cur][0] + aofs[i]);
#pragma unroll
        for (int j = 0; j < 8; j++) bfr[j] = *(const bf16x8*)(&Bs[cur][0] + bofs[j]);
#pragma unroll
        for (int i = 0; i < 2; i++)
#pragma unroll
            for (int j = 0; j < 8; j++)
                acc[i][j] = __builtin_amdgcn_mfma_f32_16x16x32_bf16(af[i], bfr[j], acc[i][j], 0, 0, 0);
    }

    // in-lane epilogue.  C/D layout (m89): col=lane&15 (per 16-tile), row=quad*4+reg
    float locv[8];
#pragma unroll
    for (int j = 0; j < 8; j++) {
        const int col = bn * 128 + 16 * j + r16;
        locv[j] = (col < NV) ? loc[col] : 0.0f;
    }

    float* yp = Ypart + ((size_t)bn * MM + (size_t)bm * 128) * OUT_F;
#pragma unroll
    for (int i = 0; i < 2; i++) {
#pragma unroll
        for (int r = 0; r < 4; r++) {
            const int tl = 32 * wave + 16 * i + 4 * quad + r;
            float v0 = 0.0f, v1 = 0.0f;
#pragma unroll
            for (int c = 0; c < 4; c++) {
                const float w = xs[tl][c];
                v0 += w * (acc[i][2 * c][r]     + locv[2 * c]);
                v1 += w * (acc[i][2 * c + 1][r] + locv[2 * c + 1]);
            }
            yp[(size_t)tl * OUT_F + r16]      = v0;
            yp[(size_t)tl * OUT_F + 16 + r16] = v1;
        }
    }
}

// ---------------------------------------------------------------------------
// Kernel 3: reduce 17 partials -> y
// ---------------------------------------------------------------------------
__global__ __launch_bounds__(256) void reduce_y_k(const float4* __restrict__ yp,
                                                  float4* __restrict__ y) {
    const size_t i = (size_t)blockIdx.x * 256 + threadIdx.x;   // MM*32/4
    float4 s = yp[i];
#pragma unroll
    for (int b = 1; b < NBN; b++) {
        float4 v = yp[i + (size_t)b * (MM * OUT_F / 4)];
        s.x += v.x; s.y += v.y; s.z += v.z; s.w += v.w;
    }
    y[i] = s;
}

// ---------------------------------------------------------------------------
extern "C" void kernel_launch(void* const* d_in, const int* in_sizes, int n_in,
                              void* d_out, int out_size, void* d_ws, size_t ws_size,
                              hipStream_t stream) {
    const float* x      = (const float*)d_in[0];
    const float* eps    = (const float*)d_in[1];
    const float* loc    = (const float*)d_in[2];
    const float* logvar = (const float*)d_in[3];
    const float* cov    = (const float*)d_in[4];
    float* y = (float*)d_out;

    char* ws = (char*)d_ws;
    __hip_bfloat16* EpsB  = (__hip_bfloat16*)ws;                                  // MM*KK bf16 (68.2 MB)
    __hip_bfloat16* LB    = (__hip_bfloat16*)(ws + (size_t)MM * KK * 2);          // NPAD*KK bf16 (9.1 MB)
    float*          Ypart = (float*)(ws + (size_t)MM * KK * 2
                                        + (size_t)NPAD * KK * 2);                 // 17*MM*32 fp32 (35.7 MB)

    prep_k<<<NB_CVT + NB_L, 256, 0, stream>>>(cov, logvar, (const float4*)eps,
                                              (uint4*)EpsB, LB);
    gemm_zl_k<<<dim3(MM / 128, NBN), 256, 0, stream>>>(EpsB, LB, loc, x, Ypart);
    reduce_y_k<<<(MM * OUT_F / 4) / 256, 256, 0, stream>>>((const float4*)Ypart, (float4*)y);
}

// Round 6
// 315.972 us; speedup vs baseline: 1.1613x; 1.0227x over previous
//
#include <hip/hip_runtime.h>
#include <hip/hip_bf16.h>

// Problem constants (BayesianLinear): IN_F=64, OUT_F=32, N=2080, B*S=16384
#define IN_F  64
#define OUT_F 32
#define NV    2080           // N
#define NPAD  2176           // 17*128
#define MM    16384          // tokens
#define KK    2080           // contraction dim
#define NBN   17             // column tiles

typedef __attribute__((ext_vector_type(4))) float f32x4;
typedef __bf16 bf16x8 __attribute__((ext_vector_type(8)));

using gas_ptr = const __attribute__((address_space(1))) void*;
using lds_ptr = __attribute__((address_space(3))) void*;

// ---------------------------------------------------------------------------
// Kernel 1: build L (bf16, row-major [NPAD][KK]); rows >= NV are zero.
// ---------------------------------------------------------------------------
__global__ __launch_bounds__(256) void build_L_k(const float* __restrict__ cov,
                                                 const float* __restrict__ logvar,
                                                 __hip_bfloat16* __restrict__ LB) {
    const int idx = blockIdx.x * 256 + threadIdx.x;   // over NPAD*KK
    const int m = idx / KK;
    const int k = idx - m * KK;
    float v = 0.0f;
    if (m < NV) {
        if (k < m)       v = cov[(size_t)(m * (m - 1) / 2) + k];
        else if (k == m) v = expf(0.5f * logvar[m]);
    }
    LB[idx] = __float2bfloat16(v);
}

// ---------------------------------------------------------------------------
// Kernel 2: fused cvt + GEMM + in-lane x-contraction.
// A (eps, fp32) is read to REGISTERS (4x dwordx4/thread), converted to bf16
// in-reg, ds_write_b128'd into the R2-proven swizzled bf16 LDS layout
// (slot(row,p) holds global part p^((row>>1)&3)); fragment reads unchanged
// (0 bank conflicts).  B (L, bf16) stays on global_load_lds.  Double-buffered
// single-barrier pipeline: loads for kb+1 issue before the MFMA block of kb
// and are consumed (cvt+ds_write) after it; next barrier drains lgkm+vm.
// Wave tiling: 4 row-strips of 32 rows x full 128 cols (acc[2][8]) so the
// x-contraction is fully in-register; partial y -> Ypart slab bn.
// Column mapping: col=128bn+16j+r16 -> c=j>>1, k=16*(j&1)+r16;
// bn==0,c==0 is the bias region (weight 1).  kblocks=min(65,4bn+4).
// ---------------------------------------------------------------------------
__global__ __launch_bounds__(256) void gemm_zl_k(const float* __restrict__ A,
                                                 const __hip_bfloat16* __restrict__ BT,
                                                 const float* __restrict__ loc,
                                                 const float* __restrict__ x,
                                                 float* __restrict__ Ypart) {
    __shared__ __align__(16) __hip_bfloat16 As[2][128 * 32];
    __shared__ __align__(16) __hip_bfloat16 Bs[2][128 * 32];
    __shared__ float xs[128][4];

    const int tid  = threadIdx.x;
    const int bm   = blockIdx.x;             // 0..127 (M tiles)
    const int bn   = (NBN - 1) - blockIdx.y; // 0..16, heaviest (bn=16) first
    const int wave = tid >> 6;
    const int lane = tid & 63;
    const int quad = lane >> 4;              // 0..3
    const int r16  = lane & 15;

    const int kblocks = min(KK / 32, 4 * bn + 4);   // triangular truncation

    // stage xs: weight for h = 4bn-1+c; bias (1.0) at bn==0,c==0; 0 if h invalid
    {
        const int tl = tid >> 1;
        const int cc = (tid & 1) * 2;
#pragma unroll
        for (int c = cc; c < cc + 2; c++) {
            const int h = 4 * bn - 1 + c;
            float w = 0.0f;
            if (bn == 0 && c == 0)          w = 1.0f;
            else if (h >= 0 && h < IN_F)    w = x[(size_t)(bm * 128 + tl) * IN_F + h];
            xs[tl][c] = w;
        }
    }

    const float*          Ag = A  + (size_t)bm * 128 * KK;   // fp32 eps tile
    const __hip_bfloat16* Bg = BT + (size_t)bn * 128 * KK;

    // chunk mapping (both operands): 512 chunks; chunk c -> slot (c>>2, c&3),
    // holding global part (c&3)^((row>>1)&3); offset row*KK + part*8 elements.
    const int c0 = tid, c1 = tid + 256;
    const int ar0 = c0 >> 2, ap0 = (c0 & 3) ^ ((ar0 >> 1) & 3);
    const int ar1 = c1 >> 2, ap1 = (c1 & 3) ^ ((ar1 >> 1) & 3);
    const size_t gofs0 = (size_t)ar0 * KK + ap0 * 8;
    const size_t gofs1 = (size_t)ar1 * KK + ap1 * 8;

    f32x4 acc[2][8];
#pragma unroll
    for (int i = 0; i < 2; i++)
#pragma unroll
        for (int j = 0; j < 8; j++) acc[i][j] = f32x4{0.f, 0.f, 0.f, 0.f};

    // fragment-read LDS offsets (elements), swizzled — identical to R2/R5
    int aofs[2], bofs[8];
#pragma unroll
    for (int i = 0; i < 2; i++) {
        const int arow = 32 * wave + 16 * i + r16;
        aofs[i] = arow * 32 + (quad ^ ((arow >> 1) & 3)) * 8;
    }
#pragma unroll
    for (int j = 0; j < 8; j++) {
        const int brow = 16 * j + r16;
        bofs[j] = brow * 32 + (quad ^ ((brow >> 1) & 3)) * 8;
    }

    // --- prologue: stage tile 0 ---
    {
        f32x4 ra0 = *(const f32x4*)(Ag + gofs0);
        f32x4 ra1 = *(const f32x4*)(Ag + gofs0 + 4);
        f32x4 ra2 = *(const f32x4*)(Ag + gofs1);
        f32x4 ra3 = *(const f32x4*)(Ag + gofs1 + 4);
        __builtin_amdgcn_global_load_lds((gas_ptr)(Bg + gofs0), (lds_ptr)(&Bs[0][0] + c0 * 8), 16, 0, 0);
        __builtin_amdgcn_global_load_lds((gas_ptr)(Bg + gofs1), (lds_ptr)(&Bs[0][0] + c1 * 8), 16, 0, 0);
        bf16x8 w0, w1;
#pragma unroll
        for (int q = 0; q < 4; q++) {
            w0[q] = (__bf16)ra0[q]; w0[4 + q] = (__bf16)ra1[q];
            w1[q] = (__bf16)ra2[q]; w1[4 + q] = (__bf16)ra3[q];
        }
        *(bf16x8*)(&As[0][0] + c0 * 8) = w0;
        *(bf16x8*)(&As[0][0] + c1 * 8) = w1;
    }

    for (int kb = 0; kb < kblocks; ++kb) {
        const int cur = kb & 1;
        __syncthreads();   // drains vm (B glds) + lgkm (A ds_write): buf[cur] ready

        const bool pf = (kb + 1 < kblocks);
        f32x4 ra0, ra1, ra2, ra3;
        if (pf) {   // issue A loads + B glds for kb+1 BEFORE the MFMA block
            const size_t k0 = (size_t)(kb + 1) * 32;
            ra0 = *(const f32x4*)(Ag + k0 + gofs0);
            ra1 = *(const f32x4*)(Ag + k0 + gofs0 + 4);
            ra2 = *(const f32x4*)(Ag + k0 + gofs1);
            ra3 = *(const f32x4*)(Ag + k0 + gofs1 + 4);
            __builtin_amdgcn_global_load_lds((gas_ptr)(Bg + k0 + gofs0), (lds_ptr)(&Bs[cur ^ 1][0] + c0 * 8), 16, 0, 0);
            __builtin_amdgcn_global_load_lds((gas_ptr)(Bg + k0 + gofs1), (lds_ptr)(&Bs[cur ^ 1][0] + c1 * 8), 16, 0, 0);
        }

        bf16x8 af[2], bfr[8];
#pragma unroll
        for (int i = 0; i < 2; i++) af[i]  = *(const bf16x8*)(&As[cur][0] + aofs[i]);
#pragma unroll
        for (int j = 0; j < 8; j++) bfr[j] = *(const bf16x8*)(&Bs[cur][0] + bofs[j]);
#pragma unroll
        for (int i = 0; i < 2; i++)
#pragma unroll
            for (int j = 0; j < 8; j++)
                acc[i][j] = __builtin_amdgcn_mfma_f32_16x16x32_bf16(af[i], bfr[j], acc[i][j], 0, 0, 0);

        if (pf) {   // cvt + ds_write after MFMAs (loads had the MFMA block to land)
            bf16x8 w0, w1;
#pragma unroll
            for (int q = 0; q < 4; q++) {
                w0[q] = (__bf16)ra0[q]; w0[4 + q] = (__bf16)ra1[q];
                w1[q] = (__bf16)ra2[q]; w1[4 + q] = (__bf16)ra3[q];
            }
            *(bf16x8*)(&As[cur ^ 1][0] + c0 * 8) = w0;
            *(bf16x8*)(&As[cur ^ 1][0] + c1 * 8) = w1;
        }
    }

    // in-lane epilogue.  C/D layout (m89): col=lane&15 (per 16-tile), row=quad*4+reg
    float locv[8];
#pragma unroll
    for (int j = 0; j < 8; j++) {
        const int col = bn * 128 + 16 * j + r16;
        locv[j] = (col < NV) ? loc[col] : 0.0f;
    }

    float* yp = Ypart + ((size_t)bn * MM + (size_t)bm * 128) * OUT_F;
#pragma unroll
    for (int i = 0; i < 2; i++) {
#pragma unroll
        for (int r = 0; r < 4; r++) {
            const int tl = 32 * wave + 16 * i + 4 * quad + r;
            float v0 = 0.0f, v1 = 0.0f;
#pragma unroll
            for (int c = 0; c < 4; c++) {
                const float w = xs[tl][c];
                v0 += w * (acc[i][2 * c][r]     + locv[2 * c]);
                v1 += w * (acc[i][2 * c + 1][r] + locv[2 * c + 1]);
            }
            yp[(size_t)tl * OUT_F + r16]      = v0;
            yp[(size_t)tl * OUT_F + 16 + r16] = v1;
        }
    }
}

// ---------------------------------------------------------------------------
// Kernel 3: reduce 17 partials -> y
// ---------------------------------------------------------------------------
__global__ __launch_bounds__(256) void reduce_y_k(const float4* __restrict__ yp,
                                                  float4* __restrict__ y) {
    const size_t i = (size_t)blockIdx.x * 256 + threadIdx.x;   // MM*32/4
    float4 s = yp[i];
#pragma unroll
    for (int b = 1; b < NBN; b++) {
        float4 v = yp[i + (size_t)b * (MM * OUT_F / 4)];
        s.x += v.x; s.y += v.y; s.z += v.z; s.w += v.w;
    }
    y[i] = s;
}

// ---------------------------------------------------------------------------
extern "C" void kernel_launch(void* const* d_in, const int* in_sizes, int n_in,
                              void* d_out, int out_size, void* d_ws, size_t ws_size,
                              hipStream_t stream) {
    const float* x      = (const float*)d_in[0];
    const float* eps    = (const float*)d_in[1];
    const float* loc    = (const float*)d_in[2];
    const float* logvar = (const float*)d_in[3];
    const float* cov    = (const float*)d_in[4];
    float* y = (float*)d_out;

    char* ws = (char*)d_ws;
    __hip_bfloat16* LB    = (__hip_bfloat16*)ws;                             // NPAD*KK bf16 (9.1 MB)
    float*          Ypart = (float*)(ws + (size_t)NPAD * KK * 2);            // 17*MM*32 fp32 (35.7 MB)

    build_L_k<<<(NPAD * KK) / 256, 256, 0, stream>>>(cov, logvar, LB);
    gemm_zl_k<<<dim3(MM / 128, NBN), 256, 0, stream>>>(eps, LB, loc, x, Ypart);
    reduce_y_k<<<(MM * OUT_F / 4) / 256, 256, 0, stream>>>((const float4*)Ypart, (float4*)y);
}